// Round 1
// baseline (3640.858 us; speedup 1.0000x reference)
//
#include <hip/hip_runtime.h>

#define DIM    384
#define DIM_Q  192
#define HEADS  8
#define HEAD_D 24
#define BATCH  4
#define HH     256
#define WW     256
#define NWIN   32
#define SCALE  0.20412414523193154f  /* 24^-0.5 */

// One workgroup (256 threads) per 8x8 spatial tile of one batch image.
// Phases:
//  1. For each of 4 channel groups g (96 ch): stage x chunk (96x64) to LDS,
//     accumulate q partials (192x64, registers), compute kv rows [96g,96g+96)
//     x 16 downsampled positions via on-the-fly DWT (Hadamard of 2x2 block).
//  2. M[h] = SCALE * k_h^T v_h  (24x24 per head) from kv in LDS.
//  3. feat = q @ M per head (attention is linear: no softmax in reference).
//  4. out = proj_w @ feat + proj_b, streamed to global.
__global__ __launch_bounds__(256) void wave_attn_fused(
    const float* __restrict__ x, const float* __restrict__ q_w,
    const float* __restrict__ kv_w, const float* __restrict__ proj_w,
    const float* __restrict__ proj_b, float* __restrict__ out)
{
    __shared__ float qbuf[DIM_Q * 64];   // 48 KB: q, later reused for feat
    __shared__ float kvbuf[DIM * 16];    // 24 KB: rows 0..191 = k, 192..383 = v
    __shared__ float xs[96 * 64];        // 24 KB: x chunk; reused for M (4608 floats)
    float* mbuf = xs;                    // alias, valid after phase 1

    const int t   = threadIdx.x;
    const int blk = blockIdx.x;
    const int b   = blk >> 10;
    const int wy  = (blk >> 5) & 31;
    const int wx  = blk & 31;
    const int by  = wy * 8, bx = wx * 8;

    const int tx = t & 15;   // position group: positions tx*4 .. tx*4+3
    const int ty = t >> 4;   // [0,16)

    // kv assignment: 16 positions (4x4) x 96 rows; thread = (pos=tx, rowblk=ty)
    const int i2 = (tx >> 2) * 2;   // local row of top-left of 2x2 block
    const int j2 = (tx & 3) * 2;    // local col

    float4 accq[12];
#pragma unroll
    for (int i = 0; i < 12; ++i) accq[i] = make_float4(0.f, 0.f, 0.f, 0.f);

    for (int g = 0; g < 4; ++g) {
        // ---- stage x chunk: channels [96g, 96g+96), 8x8 spatial ----
#pragma unroll
        for (int k = 0; k < 6; ++k) {
            int idx = t + (k << 8);          // [0,1536)
            int f  = idx & 1;
            int pi = (idx >> 1) & 7;
            int cl = idx >> 4;               // [0,96)
            const float4 v = *(const float4*)(
                x + (((size_t)(b * DIM + g * 96 + cl) * HH + by + pi) * WW + bx + f * 4));
            *(float4*)&xs[cl * 64 + pi * 8 + f * 4] = v;
        }
        __syncthreads();

        // ---- q partial: q[o, p] += q_w[o, 96g+c] * x[c, p] ----
        for (int c4 = 0; c4 < 24; ++c4) {
            const float4 xv0 = *(const float4*)&xs[(c4 * 4 + 0) * 64 + tx * 4];
            const float4 xv1 = *(const float4*)&xs[(c4 * 4 + 1) * 64 + tx * 4];
            const float4 xv2 = *(const float4*)&xs[(c4 * 4 + 2) * 64 + tx * 4];
            const float4 xv3 = *(const float4*)&xs[(c4 * 4 + 3) * 64 + tx * 4];
#pragma unroll
            for (int i = 0; i < 12; ++i) {
                const float4 w = *(const float4*)(q_w + (ty + 16 * i) * DIM + g * 96 + c4 * 4);
                accq[i].x += w.x * xv0.x + w.y * xv1.x + w.z * xv2.x + w.w * xv3.x;
                accq[i].y += w.x * xv0.y + w.y * xv1.y + w.z * xv2.y + w.w * xv3.y;
                accq[i].z += w.x * xv0.z + w.y * xv1.z + w.z * xv2.z + w.w * xv3.z;
                accq[i].w += w.x * xv0.w + w.y * xv1.w + w.z * xv2.w + w.w * xv3.w;
            }
        }

        // ---- kv rows for this group: on-the-fly DWT ----
        {
            float acck[6] = {0.f, 0.f, 0.f, 0.f, 0.f, 0.f};
            for (int cl = 0; cl < 96; ++cl) {
                const float a  = xs[cl * 64 + i2 * 8 + j2];
                const float bb = xs[cl * 64 + i2 * 8 + j2 + 1];
                const float cv = xs[cl * 64 + (i2 + 1) * 8 + j2];
                const float dv = xs[cl * 64 + (i2 + 1) * 8 + j2 + 1];
                const float ll = 0.5f * (a + bb + cv + dv);
                const float lh = 0.5f * (cv + dv - a - bb);
                const float hl = 0.5f * (bb + dv - a - cv);
                const float hh = 0.5f * (a + dv - bb - cv);
#pragma unroll
                for (int rr = 0; rr < 6; ++rr) {
                    const float4 w = *(const float4*)(kv_w + (g * 96 + ty * 6 + rr) * DIM + cl * 4);
                    acck[rr] += w.x * ll + w.y * lh + w.z * hl + w.w * hh;
                }
            }
#pragma unroll
            for (int rr = 0; rr < 6; ++rr)
                kvbuf[(g * 96 + ty * 6 + rr) * 16 + tx] = acck[rr];
        }
        __syncthreads();   // xs reuse next iter; kvbuf complete for this group
    }

    // ---- spill q to LDS (xs is free now; kvbuf final) ----
#pragma unroll
    for (int i = 0; i < 12; ++i)
        *(float4*)&qbuf[(ty + 16 * i) * 64 + tx * 4] = accq[i];

    // ---- phase 2: M[h][d1][d2] = SCALE * sum_p k[h*24+d1,p] * v[h*24+d2,p] ----
    if (t < DIM_Q) {
        const int h = t / 24, d1 = t % 24;
        float kvals[16];
#pragma unroll
        for (int p = 0; p < 16; ++p) kvals[p] = kvbuf[(h * 24 + d1) * 16 + p];
        for (int d2 = 0; d2 < 24; ++d2) {
            float s = 0.f;
#pragma unroll
            for (int p = 0; p < 16; ++p)
                s += kvals[p] * kvbuf[(DIM_Q + h * 24 + d2) * 16 + p];
            mbuf[(h * 24 + d1) * 24 + d2] = SCALE * s;
        }
    }
    __syncthreads();

    // ---- phase 3: feat[ch, p] = sum_d' q[h*24+d', p] * M[h][d'][ch%24] ----
    float4 featacc[12];
#pragma unroll
    for (int i = 0; i < 12; ++i) {
        const int ch = ty + 16 * i;
        const int h = ch / 24, d = ch % 24;
        float4 acc = make_float4(0.f, 0.f, 0.f, 0.f);
        for (int dp = 0; dp < 24; ++dp) {
            const float4 qv = *(const float4*)&qbuf[(h * 24 + dp) * 64 + tx * 4];
            const float m = mbuf[(h * 24 + dp) * 24 + d];
            acc.x += m * qv.x; acc.y += m * qv.y;
            acc.z += m * qv.z; acc.w += m * qv.w;
        }
        featacc[i] = acc;
    }
    __syncthreads();   // all q reads done before overwrite
#pragma unroll
    for (int i = 0; i < 12; ++i)
        *(float4*)&qbuf[(ty + 16 * i) * 64 + tx * 4] = featacc[i];
    __syncthreads();

    // ---- phase 4: out[o, p] = proj_b[o] + sum_ch proj_w[o, ch] * feat[ch, p] ----
    float4 acco[24];
#pragma unroll
    for (int i = 0; i < 24; ++i) acco[i] = make_float4(0.f, 0.f, 0.f, 0.f);
    for (int c4 = 0; c4 < 48; ++c4) {
        const float4 f0 = *(const float4*)&qbuf[(c4 * 4 + 0) * 64 + tx * 4];
        const float4 f1 = *(const float4*)&qbuf[(c4 * 4 + 1) * 64 + tx * 4];
        const float4 f2 = *(const float4*)&qbuf[(c4 * 4 + 2) * 64 + tx * 4];
        const float4 f3 = *(const float4*)&qbuf[(c4 * 4 + 3) * 64 + tx * 4];
#pragma unroll
        for (int i = 0; i < 24; ++i) {
            const float4 w = *(const float4*)(proj_w + (ty + 16 * i) * DIM_Q + c4 * 4);
            acco[i].x += w.x * f0.x + w.y * f1.x + w.z * f2.x + w.w * f3.x;
            acco[i].y += w.x * f0.y + w.y * f1.y + w.z * f2.y + w.w * f3.y;
            acco[i].z += w.x * f0.z + w.y * f1.z + w.z * f2.z + w.w * f3.z;
            acco[i].w += w.x * f0.w + w.y * f1.w + w.z * f2.w + w.w * f3.w;
        }
    }
    const int pi = tx >> 1;
    const int pj = (tx & 1) * 4;
#pragma unroll
    for (int i = 0; i < 24; ++i) {
        const int o = ty + 16 * i;
        const float bias = proj_b[o];
        float4 r = acco[i];
        r.x += bias; r.y += bias; r.z += bias; r.w += bias;
        *(float4*)(out + (((size_t)(b * DIM + o) * HH + by + pi) * WW + bx + pj)) = r;
    }
}

extern "C" void kernel_launch(void* const* d_in, const int* in_sizes, int n_in,
                              void* d_out, int out_size, void* d_ws, size_t ws_size,
                              hipStream_t stream) {
    const float* x      = (const float*)d_in[0];
    const float* q_w    = (const float*)d_in[1];
    const float* kv_w   = (const float*)d_in[2];
    const float* proj_w = (const float*)d_in[3];
    const float* proj_b = (const float*)d_in[4];
    float* out = (float*)d_out;
    (void)in_sizes; (void)n_in; (void)out_size; (void)d_ws; (void)ws_size;

    dim3 grid(BATCH * NWIN * NWIN);   // 4096 tiles
    dim3 block(256);
    hipLaunchKernelGGL(wave_attn_fused, grid, block, 0, stream,
                       x, q_w, kv_w, proj_w, proj_b, out);
}